// Round 4
// baseline (448.879 us; speedup 1.0000x reference)
//
#include <hip/hip_runtime.h>
#include <math.h>

#define NHID 128
#define NFEAT 256
#define NCLASS 40

typedef __bf16 bf16x8 __attribute__((ext_vector_type(8)));
typedef __bf16 bf16x4 __attribute__((ext_vector_type(4)));
typedef float floatx4 __attribute__((ext_vector_type(4)));

// ===========================================================================
// CSR build via 2-level bucketed counting sort.
// Bucket = dst >> 8  (256 nodes/bucket, nbuck = ceil(N/256) = 196).
// Record = (dst&255)<<16 | src   (requires N <= 65536 -- true here, N=50000).
// ===========================================================================

// Pass A: bucket histogram. 4096 edges/block, LDS-aggregated.
__global__ __launch_bounds__(256) void bucket_hist(const int* __restrict__ edst,
                                                   int* __restrict__ bucket_counts,
                                                   int E, int nbuck) {
    __shared__ int lh[256];
    int tid = threadIdx.x;
    lh[tid] = 0;
    __syncthreads();
    int base = blockIdx.x * 4096;
#pragma unroll
    for (int k = 0; k < 16; ++k) {
        int e = base + k * 256 + tid;
        if (e < E) atomicAdd(&lh[edst[e] >> 8], 1);
    }
    __syncthreads();
    if (tid < nbuck && lh[tid]) atomicAdd(&bucket_counts[tid], lh[tid]);
}

// Scan bucket counts -> start (exclusive), cursor (= start), row_ptr[N] = E.
__global__ __launch_bounds__(256) void bucket_scan(const int* __restrict__ counts,
                                                   int* __restrict__ start,
                                                   int* __restrict__ cursor,
                                                   int* __restrict__ row_ptr,
                                                   int nbuck, int E, int N) {
    __shared__ int lds[256];
    int tid = threadIdx.x;
    int v = (tid < nbuck) ? counts[tid] : 0;
    lds[tid] = v;
    __syncthreads();
    for (int off = 1; off < 256; off <<= 1) {
        int t = (tid >= off) ? lds[tid - off] : 0;
        __syncthreads();
        lds[tid] += t;
        __syncthreads();
    }
    int excl = lds[tid] - v;
    if (tid < nbuck) { start[tid] = excl; cursor[tid] = excl; }
    if (tid == 0) { start[nbuck] = E; row_ptr[N] = E; }
}

// Pass B: scatter packed records into bucket segments. Per-block LDS
// aggregation -> one global atomic claim per (block,bucket) -> contiguous runs.
__global__ __launch_bounds__(256) void bucket_scatter(const int* __restrict__ esrc,
                                                      const int* __restrict__ edst,
                                                      int* __restrict__ cursor,
                                                      unsigned int* __restrict__ bdata,
                                                      int E, int nbuck) {
    __shared__ int lh[256];
    __shared__ int lbase[256];
    int tid = threadIdx.x;
    lh[tid] = 0;
    __syncthreads();
    int base = blockIdx.x * 4096;
    unsigned int recs[16];
    short bks[16];
    short lofs[16];
#pragma unroll
    for (int k = 0; k < 16; ++k) {
        int e = base + k * 256 + tid;
        bks[k] = -1;
        if (e < E) {
            int d = edst[e];
            int s = esrc[e];
            int b = d >> 8;
            recs[k] = ((unsigned int)(d & 255) << 16) | (unsigned int)s;
            bks[k] = (short)b;
            lofs[k] = (short)atomicAdd(&lh[b], 1);
        }
    }
    __syncthreads();
    if (tid < nbuck && lh[tid]) lbase[tid] = atomicAdd(&cursor[tid], lh[tid]);
    __syncthreads();
#pragma unroll
    for (int k = 0; k < 16; ++k) {
        if (bks[k] >= 0) bdata[lbase[bks[k]] + lofs[k]] = recs[k];
    }
}

// Pass C: one block per bucket. In-LDS counting sort of the bucket's records
// -> row_ptr (coalesced) + srcs (writes confined to one ~16KB region/block).
__global__ __launch_bounds__(256) void bucket_finalize(const unsigned int* __restrict__ bdata,
                                                       const int* __restrict__ start,
                                                       int* __restrict__ row_ptr,
                                                       int* __restrict__ srcs,
                                                       int N) {
    __shared__ int hist[256];
    __shared__ int cur[256];
    int b = blockIdx.x;
    int tid = threadIdx.x;
    int s0 = start[b];
    int cnt = start[b + 1] - s0;
    hist[tid] = 0;
    __syncthreads();
    for (int i = tid; i < cnt; i += 256) atomicAdd(&hist[bdata[s0 + i] >> 16], 1);
    __syncthreads();
    int v0 = hist[tid];
    __syncthreads();
    for (int off = 1; off < 256; off <<= 1) {
        int t = (tid >= off) ? hist[tid - off] : 0;
        __syncthreads();
        hist[tid] += t;
        __syncthreads();
    }
    int excl = hist[tid] - v0;
    cur[tid] = excl;
    int node = b * 256 + tid;
    if (node < N) row_ptr[node] = s0 + excl;
    __syncthreads();
    for (int i = tid; i < cnt; i += 256) {
        unsigned int r = bdata[s0 + i];
        int p = atomicAdd(&cur[r >> 16], 1);
        srcs[s0 + p] = (int)(r & 0xffffu);
    }
}

// ===========================================================================
// Weight prep: transpose + split fp32 W[K][128] -> Wt_hi/lo[128][K] bf16.
// ===========================================================================
template <int K>
__global__ __launch_bounds__(256) void transpose_split(const float* __restrict__ src,
                                                       __bf16* __restrict__ dhi,
                                                       __bf16* __restrict__ dlo, int total) {
    int i = blockIdx.x * 256 + threadIdx.x;
    if (i >= total) return;
    int per = 128 * K;
    int l = i / per;
    int r = i - l * per;
    int n = r / K;
    int k = r - n * K;
    float v = src[(size_t)l * per + (size_t)k * 128 + n];
    __bf16 hi = (__bf16)v;
    dhi[i] = hi;
    dlo[i] = (__bf16)(v - (float)hi);
}

// ===========================================================================
// FUSED GIN layer: per block of 64 output rows,
//   phase 1: aggregate sum = h[node](hi+lo) + sum_{src} h_hi[src]
//            directly into the XOR-swizzled LDS A-tile (bf16 hi/lo),
//   phase 2: MFMA GEMM  h' = relu(A @ W + b)  (K=128), h' written hi/lo.
// Eliminates the 51 MB/layer sum round-trip through HBM/L3 and overlaps
// gather (memory pipe) with MFMA (matrix pipe) across co-resident blocks.
// LDS = 64KB: A hi/lo 2x16KB + W hi/lo 2x16KB (epilogue reuses W space).
// ===========================================================================
__global__ __launch_bounds__(256) void gin_layer_fused(
    const __bf16* __restrict__ hhi, const __bf16* __restrict__ hlo,
    const int* __restrict__ row_ptr, const int* __restrict__ srcs,
    const __bf16* __restrict__ Wthi, const __bf16* __restrict__ Wtlo,
    const float* __restrict__ bias, __bf16* __restrict__ Ohi,
    __bf16* __restrict__ Olo, int N) {
    __shared__ __align__(16) char smem[65536];
    __bf16* sAhi = (__bf16*)smem;                // 64x128 = 16KB
    __bf16* sAlo = (__bf16*)(smem + 16384);      // 16KB
    __bf16* sWhi = (__bf16*)(smem + 32768);      // 128x64 = 16KB
    __bf16* sWlo = (__bf16*)(smem + 49152);      // 16KB

    int tid = threadIdx.x;
    int wave = tid >> 6;
    int lane = tid & 63;
    int row0 = blockIdx.x * 64;

    // ---------------- phase 1: aggregate into LDS A ----------------
    int g = lane >> 4;   // edge slot 0..3
    int c = lane & 15;   // 16B chunk (8 bf16 feats): cols c*8..c*8+7
    const bf16x8* hv = (const bf16x8*)hhi;

    // hoist this wave's 17 row_ptr entries (coalesced, one load)
    int rpl = 0;
    {
        int idx = row0 + wave * 16 + lane;
        if (lane <= 16 && idx <= N) rpl = row_ptr[idx];
    }

    for (int t = 0; t < 16; ++t) {
        int r = wave * 16 + t;
        int node = row0 + r;
        // swizzled LDS position for (row r, chunk c):
        int off = r * 128 + ((c >> 3) << 6) + (((c & 7) ^ (r & 7)) << 3);
        if (node >= N) {
            if (g == 0) {
                bf16x8 z;
#pragma unroll
                for (int j = 0; j < 8; ++j) z[j] = (__bf16)0.f;
                *(bf16x8*)(sAhi + off) = z;
                *(bf16x8*)(sAlo + off) = z;
            }
            continue;
        }
        int beg = __shfl(rpl, t);
        int end = __shfl(rpl, t + 1);

        // self-row hi/lo hoisted ahead of the edge loop
        bf16x8 sh = hv[(size_t)node * 16 + c];
        bf16x8 sl = ((const bf16x8*)hlo)[(size_t)node * 16 + c];

        float a[8], b2[8];
#pragma unroll
        for (int j = 0; j < 8; ++j) { a[j] = 0.f; b2[j] = 0.f; }

        int i = beg;
        for (; i + 16 <= end; i += 16) {
            int s0 = __builtin_nontemporal_load(&srcs[i + g]);
            int s1 = __builtin_nontemporal_load(&srcs[i + 4 + g]);
            int s2 = __builtin_nontemporal_load(&srcs[i + 8 + g]);
            int s3 = __builtin_nontemporal_load(&srcs[i + 12 + g]);
            bf16x8 v0 = hv[(size_t)s0 * 16 + c];
            bf16x8 v1 = hv[(size_t)s1 * 16 + c];
            bf16x8 v2 = hv[(size_t)s2 * 16 + c];
            bf16x8 v3 = hv[(size_t)s3 * 16 + c];
#pragma unroll
            for (int j = 0; j < 8; ++j) {
                a[j] += (float)v0[j] + (float)v2[j];
                b2[j] += (float)v1[j] + (float)v3[j];
            }
        }
        for (; i + 8 <= end; i += 8) {
            int s0 = __builtin_nontemporal_load(&srcs[i + g]);
            int s1 = __builtin_nontemporal_load(&srcs[i + 4 + g]);
            bf16x8 v0 = hv[(size_t)s0 * 16 + c];
            bf16x8 v1 = hv[(size_t)s1 * 16 + c];
#pragma unroll
            for (int j = 0; j < 8; ++j) { a[j] += (float)v0[j]; b2[j] += (float)v1[j]; }
        }
        for (; i < end; i += 4) {
            if (i + g < end) {
                int s = __builtin_nontemporal_load(&srcs[i + g]);
                bf16x8 v = hv[(size_t)s * 16 + c];
#pragma unroll
                for (int j = 0; j < 8; ++j) a[j] += (float)v[j];
            }
        }
#pragma unroll
        for (int j = 0; j < 8; ++j) a[j] += b2[j];
#pragma unroll
        for (int j = 0; j < 8; ++j) a[j] += __shfl_xor(a[j], 16);
#pragma unroll
        for (int j = 0; j < 8; ++j) a[j] += __shfl_xor(a[j], 32);

        if (g == 0) {
            bf16x8 whi, wlo;
#pragma unroll
            for (int j = 0; j < 8; ++j) {
                float v = a[j] + (float)sh[j] + (float)sl[j];
                __bf16 h = (__bf16)v;
                whi[j] = h;
                wlo[j] = (__bf16)(v - (float)h);
            }
            *(bf16x8*)(sAhi + off) = whi;
            *(bf16x8*)(sAlo + off) = wlo;
        }
    }
    __syncthreads();

    // ---------------- phase 2: MFMA GEMM (A resident in LDS) ----------------
    int m16 = lane & 15;
    int q = lane >> 4;
    int axor = m16 & 7;
    int arow = wave * 16 + m16;

    floatx4 acc[8];
#pragma unroll
    for (int t = 0; t < 8; ++t) acc[t] = (floatx4){0.f, 0.f, 0.f, 0.f};

    for (int k0 = 0; k0 < 128; k0 += 64) {
        // stage W tile (128 x 64)
#pragma unroll
        for (int it = 0; it < 4; ++it) {
            int lin = it * 2048 + tid * 8;
            int n = lin >> 6, kk = lin & 63;
            int off = n * 64 + (((kk >> 3) ^ (n & 7)) << 3);
            *(bf16x8*)(sWhi + off) = *(const bf16x8*)&Wthi[(size_t)n * 128 + k0 + kk];
            *(bf16x8*)(sWlo + off) = *(const bf16x8*)&Wtlo[(size_t)n * 128 + k0 + kk];
        }
        __syncthreads();

#pragma unroll
        for (int s = 0; s < 2; ++s) {
            int sw = (((s * 4 + q) ^ axor) << 3);
            bf16x8 ahi = *(bf16x8*)(sAhi + arow * 128 + k0 + sw);
            bf16x8 alo = *(bf16x8*)(sAlo + arow * 128 + k0 + sw);
#pragma unroll
            for (int t = 0; t < 8; ++t) {
                int n = t * 16 + m16;
                bf16x8 bhi = *(bf16x8*)(sWhi + n * 64 + sw);
                bf16x8 blo = *(bf16x8*)(sWlo + n * 64 + sw);
                acc[t] = __builtin_amdgcn_mfma_f32_16x16x32_bf16(ahi, bhi, acc[t], 0, 0, 0);
                acc[t] = __builtin_amdgcn_mfma_f32_16x16x32_bf16(alo, bhi, acc[t], 0, 0, 0);
                acc[t] = __builtin_amdgcn_mfma_f32_16x16x32_bf16(ahi, blo, acc[t], 0, 0, 0);
            }
        }
        __syncthreads();
    }

    // ---- epilogue: bias + relu -> fp32 LDS (reuses W space) -> bf16 hi/lo ----
    float* eps = (float*)(smem + 32768);  // 64*128*4 = 32KB
#pragma unroll
    for (int t = 0; t < 8; ++t) {
        int col = t * 16 + m16;
        float bb = bias[col];
#pragma unroll
        for (int i = 0; i < 4; ++i) {
            int row = wave * 16 + q * 4 + i;
            eps[row * 128 + col] = fmaxf(acc[t][i] + bb, 0.f);
        }
    }
    __syncthreads();
#pragma unroll
    for (int it = 0; it < 8; ++it) {
        int lin = it * 1024 + tid * 4;
        int row = lin >> 7, col = lin & 127;
        int gg = row0 + row;
        if (gg < N) {
            float4 v = *(float4*)(eps + lin);
            bf16x4 hi, lo;
            float vv[4] = {v.x, v.y, v.z, v.w};
#pragma unroll
            for (int j = 0; j < 4; ++j) {
                __bf16 h = (__bf16)vv[j];
                hi[j] = h;
                lo[j] = (__bf16)(vv[j] - (float)h);
            }
            *(bf16x4*)&Ohi[(size_t)gg * 128 + col] = hi;
            *(bf16x4*)&Olo[(size_t)gg * 128 + col] = lo;
        }
    }
}

// ===========================================================================
// Input-layer MFMA GEMM: out = relu(x @ W_in + b), K=256, fp32 A split in
// staging. Tile 64x128, BK=64, XOR-swizzled LDS, triple MFMA.
// ===========================================================================
__global__ __launch_bounds__(256) void gemm_in(
    const float* __restrict__ Af,
    const __bf16* __restrict__ Wthi, const __bf16* __restrict__ Wtlo,
    const float* __restrict__ bias, __bf16* __restrict__ Ohi,
    __bf16* __restrict__ Olo, int M, int K) {
    __shared__ __align__(16) char smem[49152];
    __bf16* sAhi = (__bf16*)smem;                // 64x64 = 8KB
    __bf16* sAlo = (__bf16*)(smem + 8192);       // 8KB
    __bf16* sWhi = (__bf16*)(smem + 16384);      // 128x64 = 16KB
    __bf16* sWlo = (__bf16*)(smem + 32768);      // 16KB

    int tid = threadIdx.x;
    int row0 = blockIdx.x * 64;
    int wave = tid >> 6;
    int l = tid & 63;
    int m16 = l & 15;
    int q = l >> 4;
    int axor = m16 & 7;
    int arow = wave * 16 + m16;

    floatx4 acc[8];
#pragma unroll
    for (int t = 0; t < 8; ++t) acc[t] = (floatx4){0.f, 0.f, 0.f, 0.f};

    for (int k0 = 0; k0 < K; k0 += 64) {
        // ---- stage A tile (64 x 64), fp32 -> bf16 hi/lo ----
#pragma unroll
        for (int it = 0; it < 2; ++it) {
            int lin = it * 2048 + tid * 8;
            int row = lin >> 6, k = lin & 63;
            int g = min(row0 + row, M - 1);
            int off = row * 64 + (((k >> 3) ^ (row & 7)) << 3);
            float4 v0 = *(const float4*)&Af[(size_t)g * K + k0 + k];
            float4 v1 = *(const float4*)&Af[(size_t)g * K + k0 + k + 4];
            float s[8] = {v0.x, v0.y, v0.z, v0.w, v1.x, v1.y, v1.z, v1.w};
            bf16x8 shi, slo;
#pragma unroll
            for (int j = 0; j < 8; ++j) {
                __bf16 h = (__bf16)s[j];
                shi[j] = h;
                slo[j] = (__bf16)(s[j] - (float)h);
            }
            *(bf16x8*)(sAhi + off) = shi;
            *(bf16x8*)(sAlo + off) = slo;
        }
        // ---- stage W tile (128 x 64) ----
#pragma unroll
        for (int it = 0; it < 4; ++it) {
            int lin = it * 2048 + tid * 8;
            int n = lin >> 6, kk = lin & 63;
            int off = n * 64 + (((kk >> 3) ^ (n & 7)) << 3);
            *(bf16x8*)(sWhi + off) = *(const bf16x8*)&Wthi[(size_t)n * K + k0 + kk];
            *(bf16x8*)(sWlo + off) = *(const bf16x8*)&Wtlo[(size_t)n * K + k0 + kk];
        }
        __syncthreads();

#pragma unroll
        for (int s = 0; s < 2; ++s) {
            int sw = (((s * 4 + q) ^ axor) << 3);
            bf16x8 ahi = *(bf16x8*)(sAhi + arow * 64 + sw);
            bf16x8 alo = *(bf16x8*)(sAlo + arow * 64 + sw);
#pragma unroll
            for (int t = 0; t < 8; ++t) {
                int n = t * 16 + m16;
                bf16x8 bhi = *(bf16x8*)(sWhi + n * 64 + sw);
                bf16x8 blo = *(bf16x8*)(sWlo + n * 64 + sw);
                acc[t] = __builtin_amdgcn_mfma_f32_16x16x32_bf16(ahi, bhi, acc[t], 0, 0, 0);
                acc[t] = __builtin_amdgcn_mfma_f32_16x16x32_bf16(alo, bhi, acc[t], 0, 0, 0);
                acc[t] = __builtin_amdgcn_mfma_f32_16x16x32_bf16(ahi, blo, acc[t], 0, 0, 0);
            }
        }
        __syncthreads();
    }

    // ---- epilogue: bias + relu -> fp32 LDS -> coalesced bf16 hi/lo ----
    float* eps = (float*)(smem + 16384);  // 64*128*4 = 32KB
#pragma unroll
    for (int t = 0; t < 8; ++t) {
        int col = t * 16 + m16;
        float bb = bias[col];
#pragma unroll
        for (int i = 0; i < 4; ++i) {
            int row = wave * 16 + q * 4 + i;
            eps[row * 128 + col] = fmaxf(acc[t][i] + bb, 0.f);
        }
    }
    __syncthreads();
#pragma unroll
    for (int it = 0; it < 8; ++it) {
        int lin = it * 1024 + tid * 4;
        int row = lin >> 7, col = lin & 127;
        int g = row0 + row;
        if (g < M) {
            float4 v = *(float4*)(eps + lin);
            bf16x4 hi, lo;
            float vv[4] = {v.x, v.y, v.z, v.w};
#pragma unroll
            for (int j = 0; j < 4; ++j) {
                __bf16 h = (__bf16)vv[j];
                hi[j] = h;
                lo[j] = (__bf16)(vv[j] - (float)h);
            }
            *(bf16x4*)&Ohi[(size_t)g * 128 + col] = hi;
            *(bf16x4*)&Olo[(size_t)g * 128 + col] = lo;
        }
    }
}

// ===========================================================================
// Output: logits = h @ W_out + b_out (K=128, C=40), then row log_softmax.
// ===========================================================================
__global__ __launch_bounds__(256) void out_logsoftmax(const __bf16* __restrict__ hhi,
                                                      const __bf16* __restrict__ hlo,
                                                      const float* __restrict__ Wout,
                                                      const float* __restrict__ bout,
                                                      float* __restrict__ out, int M) {
    __shared__ float sW[128 * NCLASS];
    __shared__ float sb[NCLASS];
    __shared__ float sH[32 * 132];
    int tid = threadIdx.x;
    for (int i = tid; i < 128 * NCLASS; i += 256) sW[i] = Wout[i];
    if (tid < NCLASS) sb[tid] = bout[tid];
    int row0 = blockIdx.x * 32;
#pragma unroll
    for (int it = 0; it < 4; ++it) {
        int i = tid * 4 + it * 1024;
        int r = i >> 7, k = i & 127;
        int rr = min(row0 + r, M - 1);
        uint2 uh = *(const uint2*)&hhi[(size_t)rr * 128 + k];
        uint2 ul = *(const uint2*)&hlo[(size_t)rr * 128 + k];
        sH[r * 132 + k + 0] = __uint_as_float(uh.x << 16) + __uint_as_float(ul.x << 16);
        sH[r * 132 + k + 1] = __uint_as_float(uh.x & 0xffff0000u) + __uint_as_float(ul.x & 0xffff0000u);
        sH[r * 132 + k + 2] = __uint_as_float(uh.y << 16) + __uint_as_float(ul.y << 16);
        sH[r * 132 + k + 3] = __uint_as_float(uh.y & 0xffff0000u) + __uint_as_float(ul.y & 0xffff0000u);
    }
    __syncthreads();

    int r = tid >> 3;
    int cg = tid & 7;
    float z[5];
#pragma unroll
    for (int j = 0; j < 5; ++j) z[j] = sb[cg * 5 + j];
    for (int k = 0; k < 128; ++k) {
        float a = sH[r * 132 + k];
#pragma unroll
        for (int j = 0; j < 5; ++j) z[j] += a * sW[k * NCLASS + cg * 5 + j];
    }
    float m = z[0];
#pragma unroll
    for (int j = 1; j < 5; ++j) m = fmaxf(m, z[j]);
    for (int off = 1; off < 8; off <<= 1) m = fmaxf(m, __shfl_xor(m, off));
    float s = 0.f;
#pragma unroll
    for (int j = 0; j < 5; ++j) s += expf(z[j] - m);
    for (int off = 1; off < 8; off <<= 1) s += __shfl_xor(s, off);
    float lse = m + logf(s);
    int row = row0 + r;
    if (row < M) {
#pragma unroll
        for (int j = 0; j < 5; ++j) out[(size_t)row * NCLASS + cg * 5 + j] = z[j] - lse;
    }
}

// ===========================================================================
extern "C" void kernel_launch(void* const* d_in, const int* in_sizes, int n_in,
                              void* d_out, int out_size, void* d_ws, size_t ws_size,
                              hipStream_t stream) {
    const float* x      = (const float*)d_in[0];
    const int*   esrc   = (const int*)d_in[1];
    const int*   edst   = (const int*)d_in[2];
    const float* W_in   = (const float*)d_in[3];
    const float* b_in   = (const float*)d_in[4];
    const float* W_mlps = (const float*)d_in[5];
    const float* b_mlps = (const float*)d_in[6];
    const float* W_out  = (const float*)d_in[7];
    const float* b_out  = (const float*)d_in[8];
    float* out = (float*)d_out;

    int N = in_sizes[0] / NFEAT;  // 50000
    int E = in_sizes[1];          // 800000
    int nbuck = (N + 255) >> 8;   // 196

    // workspace carve (~80.6 MB; sum slots retained only as bdata alias space)
    char* ws = (char*)d_ws;
    size_t hb = (((size_t)N * NHID * sizeof(__bf16)) + 255) & ~(size_t)255;  // 12.8MB
    __bf16* h_hi_a = (__bf16*)ws;
    __bf16* h_lo_a = (__bf16*)(ws + hb);
    __bf16* h_hi_b = (__bf16*)(ws + 2 * hb);
    __bf16* h_lo_b = (__bf16*)(ws + 3 * hb);
    // bdata lives in the (now otherwise unused) 5th/6th slots: CSR build only
    unsigned int* bdata = (unsigned int*)(ws + 4 * hb);
    char* ip = ws + 6 * hb;
    int* row_ptr = (int*)ip;  ip += (((size_t)(N + 1) * 4) + 255) & ~(size_t)255;
    int* srcs    = (int*)ip;  ip += (((size_t)E * 4) + 255) & ~(size_t)255;
    int* bucket_counts = (int*)ip;  ip += 1024;
    int* bucket_start  = (int*)ip;  ip += 1024;
    int* bucket_cursor = (int*)ip;  ip += 1024;
    __bf16* Wt_in_hi   = (__bf16*)ip;  ip += 128 * NFEAT * 2;
    __bf16* Wt_in_lo   = (__bf16*)ip;  ip += 128 * NFEAT * 2;
    __bf16* Wt_mlps_hi = (__bf16*)ip;  ip += 3 * 128 * NHID * 2;
    __bf16* Wt_mlps_lo = (__bf16*)ip;  ip += 3 * 128 * NHID * 2;

    int eb4 = (E + 4095) / 4096;

    // ---- CSR build (bucketed counting sort) ----
    hipMemsetAsync(bucket_counts, 0, 1024, stream);
    bucket_hist<<<eb4, 256, 0, stream>>>(edst, bucket_counts, E, nbuck);
    bucket_scan<<<1, 256, 0, stream>>>(bucket_counts, bucket_start, bucket_cursor,
                                       row_ptr, nbuck, E, N);
    bucket_scatter<<<eb4, 256, 0, stream>>>(esrc, edst, bucket_cursor, bdata, E, nbuck);
    bucket_finalize<<<nbuck, 256, 0, stream>>>(bdata, bucket_start, row_ptr, srcs, N);

    // ---- weight prep ----
    transpose_split<NFEAT><<<(128 * NFEAT + 255) / 256, 256, 0, stream>>>(
        W_in, Wt_in_hi, Wt_in_lo, 128 * NFEAT);
    transpose_split<NHID><<<(3 * 128 * NHID + 255) / 256, 256, 0, stream>>>(
        W_mlps, Wt_mlps_hi, Wt_mlps_lo, 3 * 128 * NHID);

    int gb = (N + 63) / 64;
    // ---- input layer ----
    gemm_in<<<gb, 256, 0, stream>>>(x, Wt_in_hi, Wt_in_lo, b_in, h_hi_a, h_lo_a, N, NFEAT);

    // ---- 3 fused GIN layers (aggregate + GEMM in one kernel) ----
    __bf16* cur_hi = h_hi_a; __bf16* cur_lo = h_lo_a;
    __bf16* nxt_hi = h_hi_b; __bf16* nxt_lo = h_lo_b;
    for (int i = 0; i < 3; ++i) {
        gin_layer_fused<<<gb, 256, 0, stream>>>(
            cur_hi, cur_lo, row_ptr, srcs,
            Wt_mlps_hi + (size_t)i * 128 * NHID, Wt_mlps_lo + (size_t)i * 128 * NHID,
            b_mlps + (size_t)i * NHID, nxt_hi, nxt_lo, N);
        __bf16* t;
        t = cur_hi; cur_hi = nxt_hi; nxt_hi = t;
        t = cur_lo; cur_lo = nxt_lo; nxt_lo = t;
    }

    // ---- output layer + log_softmax ----
    out_logsoftmax<<<(N + 31) / 32, 256, 0, stream>>>(cur_hi, cur_lo, W_out, b_out, out, N);
}

// Round 5
// 324.106 us; speedup vs baseline: 1.3850x; 1.3850x over previous
//
#include <hip/hip_runtime.h>
#include <math.h>

#define NHID 128
#define NFEAT 256
#define NCLASS 40

typedef __bf16 bf16x8 __attribute__((ext_vector_type(8)));
typedef __bf16 bf16x4 __attribute__((ext_vector_type(4)));
typedef float floatx4 __attribute__((ext_vector_type(4)));

// ===========================================================================
// CSR build via 2-level bucketed counting sort.
// Bucket = dst >> 8  (256 nodes/bucket, nbuck = ceil(N/256) = 196).
// Record = (dst&255)<<16 | src   (requires N <= 65536 -- true here, N=50000).
// ===========================================================================

// Pass A: bucket histogram. 4096 edges/block, LDS-aggregated.
__global__ __launch_bounds__(256) void bucket_hist(const int* __restrict__ edst,
                                                   int* __restrict__ bucket_counts,
                                                   int E, int nbuck) {
    __shared__ int lh[256];
    int tid = threadIdx.x;
    lh[tid] = 0;
    __syncthreads();
    int base = blockIdx.x * 4096;
#pragma unroll
    for (int k = 0; k < 16; ++k) {
        int e = base + k * 256 + tid;
        if (e < E) atomicAdd(&lh[edst[e] >> 8], 1);
    }
    __syncthreads();
    if (tid < nbuck && lh[tid]) atomicAdd(&bucket_counts[tid], lh[tid]);
}

// Scan bucket counts -> start (exclusive), cursor (= start), row_ptr[N] = E.
__global__ __launch_bounds__(256) void bucket_scan(const int* __restrict__ counts,
                                                   int* __restrict__ start,
                                                   int* __restrict__ cursor,
                                                   int* __restrict__ row_ptr,
                                                   int nbuck, int E, int N) {
    __shared__ int lds[256];
    int tid = threadIdx.x;
    int v = (tid < nbuck) ? counts[tid] : 0;
    lds[tid] = v;
    __syncthreads();
    for (int off = 1; off < 256; off <<= 1) {
        int t = (tid >= off) ? lds[tid - off] : 0;
        __syncthreads();
        lds[tid] += t;
        __syncthreads();
    }
    int excl = lds[tid] - v;
    if (tid < nbuck) { start[tid] = excl; cursor[tid] = excl; }
    if (tid == 0) { start[nbuck] = E; row_ptr[N] = E; }
}

// Pass B: scatter packed records into bucket segments. Per-block LDS
// aggregation -> one global atomic claim per (block,bucket) -> contiguous runs.
__global__ __launch_bounds__(256) void bucket_scatter(const int* __restrict__ esrc,
                                                      const int* __restrict__ edst,
                                                      int* __restrict__ cursor,
                                                      unsigned int* __restrict__ bdata,
                                                      int E, int nbuck) {
    __shared__ int lh[256];
    __shared__ int lbase[256];
    int tid = threadIdx.x;
    lh[tid] = 0;
    __syncthreads();
    int base = blockIdx.x * 4096;
    unsigned int recs[16];
    short bks[16];
    short lofs[16];
#pragma unroll
    for (int k = 0; k < 16; ++k) {
        int e = base + k * 256 + tid;
        bks[k] = -1;
        if (e < E) {
            int d = edst[e];
            int s = esrc[e];
            int b = d >> 8;
            recs[k] = ((unsigned int)(d & 255) << 16) | (unsigned int)s;
            bks[k] = (short)b;
            lofs[k] = (short)atomicAdd(&lh[b], 1);
        }
    }
    __syncthreads();
    if (tid < nbuck && lh[tid]) lbase[tid] = atomicAdd(&cursor[tid], lh[tid]);
    __syncthreads();
#pragma unroll
    for (int k = 0; k < 16; ++k) {
        if (bks[k] >= 0) bdata[lbase[bks[k]] + lofs[k]] = recs[k];
    }
}

// Pass C: one block per bucket. In-LDS counting sort of the bucket's records
// -> row_ptr (coalesced) + srcs (writes confined to one ~16KB region/block).
__global__ __launch_bounds__(256) void bucket_finalize(const unsigned int* __restrict__ bdata,
                                                       const int* __restrict__ start,
                                                       int* __restrict__ row_ptr,
                                                       int* __restrict__ srcs,
                                                       int N) {
    __shared__ int hist[256];
    __shared__ int cur[256];
    int b = blockIdx.x;
    int tid = threadIdx.x;
    int s0 = start[b];
    int cnt = start[b + 1] - s0;
    hist[tid] = 0;
    __syncthreads();
    for (int i = tid; i < cnt; i += 256) atomicAdd(&hist[bdata[s0 + i] >> 16], 1);
    __syncthreads();
    int v0 = hist[tid];
    __syncthreads();
    for (int off = 1; off < 256; off <<= 1) {
        int t = (tid >= off) ? hist[tid - off] : 0;
        __syncthreads();
        hist[tid] += t;
        __syncthreads();
    }
    int excl = hist[tid] - v0;
    cur[tid] = excl;
    int node = b * 256 + tid;
    if (node < N) row_ptr[node] = s0 + excl;
    __syncthreads();
    for (int i = tid; i < cnt; i += 256) {
        unsigned int r = bdata[s0 + i];
        int p = atomicAdd(&cur[r >> 16], 1);
        srcs[s0 + p] = (int)(r & 0xffffu);
    }
}

// ===========================================================================
// Weight prep (single dispatch): transpose + split fp32 W[K][128] ->
// Wt_hi/lo[128][K] bf16, for both W_in (K=256) and the 3 W_mlps (K=128).
// ===========================================================================
__global__ __launch_bounds__(256) void transpose_split_all(
    const float* __restrict__ Win, const float* __restrict__ Wmlps,
    __bf16* __restrict__ dInHi, __bf16* __restrict__ dInLo,
    __bf16* __restrict__ dMlHi, __bf16* __restrict__ dMlLo) {
    const int TOT_IN = 128 * NFEAT;      // 32768
    const int TOT_ML = 3 * 128 * NHID;   // 49152
    int i = blockIdx.x * 256 + threadIdx.x;
    if (i < TOT_IN) {
        int n = i / NFEAT;
        int k = i - n * NFEAT;
        float v = Win[(size_t)k * 128 + n];
        __bf16 h = (__bf16)v;
        dInHi[i] = h;
        dInLo[i] = (__bf16)(v - (float)h);
    } else if (i < TOT_IN + TOT_ML) {
        int r = i - TOT_IN;
        int per = 128 * NHID;
        int l = r / per;
        int rr = r - l * per;
        int n = rr / NHID;
        int k = rr - n * NHID;
        float v = Wmlps[(size_t)l * per + (size_t)k * 128 + n];
        __bf16 h = (__bf16)v;
        dMlHi[r] = h;
        dMlLo[r] = (__bf16)(v - (float)h);
    }
}

// ===========================================================================
// Fused aggregate: sum = h[node] (hi+lo) + sum_{src in CSR} h_hi[src],
// written as bf16 hi/lo pair. One wave/node; row = 256B = 16 lanes x 16B,
// so each gather instruction covers 4 edges; 16 edges (4 gathers) in flight.
// ===========================================================================
__global__ __launch_bounds__(256) void aggregate_fused(const __bf16* __restrict__ hhi,
                                                       const __bf16* __restrict__ hlo,
                                                       const int* __restrict__ row_ptr,
                                                       const int* __restrict__ srcs,
                                                       __bf16* __restrict__ ohi,
                                                       __bf16* __restrict__ olo, int N) {
    int tid = threadIdx.x;
    int node = blockIdx.x * 4 + (tid >> 6);
    if (node >= N) return;
    int lane = tid & 63;
    int g = lane >> 4;   // edge slot 0..3
    int c = lane & 15;   // 16B chunk (8 bf16 features)
    int beg = row_ptr[node];
    int end = row_ptr[node + 1];
    const bf16x8* hv = (const bf16x8*)hhi;

    bf16x8 sh = hv[(size_t)node * 16 + c];
    bf16x8 sl = ((const bf16x8*)hlo)[(size_t)node * 16 + c];

    float a[8], b2[8];
#pragma unroll
    for (int j = 0; j < 8; ++j) { a[j] = 0.f; b2[j] = 0.f; }

    int i = beg;
    for (; i + 16 <= end; i += 16) {
        int s0 = __builtin_nontemporal_load(&srcs[i + g]);
        int s1 = __builtin_nontemporal_load(&srcs[i + 4 + g]);
        int s2 = __builtin_nontemporal_load(&srcs[i + 8 + g]);
        int s3 = __builtin_nontemporal_load(&srcs[i + 12 + g]);
        bf16x8 v0 = hv[(size_t)s0 * 16 + c];
        bf16x8 v1 = hv[(size_t)s1 * 16 + c];
        bf16x8 v2 = hv[(size_t)s2 * 16 + c];
        bf16x8 v3 = hv[(size_t)s3 * 16 + c];
#pragma unroll
        for (int j = 0; j < 8; ++j) {
            a[j] += (float)v0[j] + (float)v2[j];
            b2[j] += (float)v1[j] + (float)v3[j];
        }
    }
    for (; i + 8 <= end; i += 8) {
        int s0 = __builtin_nontemporal_load(&srcs[i + g]);
        int s1 = __builtin_nontemporal_load(&srcs[i + 4 + g]);
        bf16x8 v0 = hv[(size_t)s0 * 16 + c];
        bf16x8 v1 = hv[(size_t)s1 * 16 + c];
#pragma unroll
        for (int j = 0; j < 8; ++j) { a[j] += (float)v0[j]; b2[j] += (float)v1[j]; }
    }
    for (; i < end; i += 4) {
        if (i + g < end) {
            int s = __builtin_nontemporal_load(&srcs[i + g]);
            bf16x8 v = hv[(size_t)s * 16 + c];
#pragma unroll
            for (int j = 0; j < 8; ++j) a[j] += (float)v[j];
        }
    }
#pragma unroll
    for (int j = 0; j < 8; ++j) a[j] += b2[j];
#pragma unroll
    for (int j = 0; j < 8; ++j) a[j] += __shfl_xor(a[j], 16);
#pragma unroll
    for (int j = 0; j < 8; ++j) a[j] += __shfl_xor(a[j], 32);

    if (g == 0) {
        bf16x8 whi, wlo;
#pragma unroll
        for (int j = 0; j < 8; ++j) {
            float v = a[j] + (float)sh[j] + (float)sl[j];
            __bf16 h = (__bf16)v;
            whi[j] = h;
            wlo[j] = (__bf16)(v - (float)h);
        }
        ((bf16x8*)ohi)[(size_t)node * 16 + c] = whi;
        ((bf16x8*)olo)[(size_t)node * 16 + c] = wlo;
    }
}

// ===========================================================================
// MFMA GEMM: out = relu(A @ W + b), N=128, split-precision bf16.
// MODE 0: A = fp32 Af[M][K] (input layer, K=256) -- split in staging.
// MODE 1: A = bf16 hi/lo pair (fused aggregate output, K=128) -- pure copy.
// Tile 64x128, BK=64, XOR-swizzled LDS, 3 MFMAs per frag (hi*hi+lo*hi+hi*lo).
// ===========================================================================
template <int MODE>
__global__ __launch_bounds__(256) void gemm_mfma(
    const float* __restrict__ Af, const __bf16* __restrict__ Ahi,
    const __bf16* __restrict__ Alo,
    const __bf16* __restrict__ Wthi, const __bf16* __restrict__ Wtlo,
    const float* __restrict__ bias, __bf16* __restrict__ Ohi,
    __bf16* __restrict__ Olo, int M, int K) {
    __shared__ __align__(16) char smem[49152];
    __bf16* sAhi = (__bf16*)smem;                // 64x64 = 8KB
    __bf16* sAlo = (__bf16*)(smem + 8192);       // 8KB
    __bf16* sWhi = (__bf16*)(smem + 16384);      // 128x64 = 16KB
    __bf16* sWlo = (__bf16*)(smem + 32768);      // 16KB

    int tid = threadIdx.x;
    int row0 = blockIdx.x * 64;
    int wave = tid >> 6;
    int l = tid & 63;
    int m16 = l & 15;
    int q = l >> 4;
    int axor = m16 & 7;
    int arow = wave * 16 + m16;

    floatx4 acc[8];
#pragma unroll
    for (int t = 0; t < 8; ++t) acc[t] = (floatx4){0.f, 0.f, 0.f, 0.f};

    for (int k0 = 0; k0 < K; k0 += 64) {
        // ---- stage A tile (64 x 64) ----
#pragma unroll
        for (int it = 0; it < 2; ++it) {
            int lin = it * 2048 + tid * 8;
            int row = lin >> 6, k = lin & 63;
            int g = min(row0 + row, M - 1);
            int off = row * 64 + (((k >> 3) ^ (row & 7)) << 3);
            if (MODE == 0) {
                float4 v0 = *(const float4*)&Af[(size_t)g * K + k0 + k];
                float4 v1 = *(const float4*)&Af[(size_t)g * K + k0 + k + 4];
                float s[8] = {v0.x, v0.y, v0.z, v0.w, v1.x, v1.y, v1.z, v1.w};
                bf16x8 shi, slo;
#pragma unroll
                for (int j = 0; j < 8; ++j) {
                    __bf16 h = (__bf16)s[j];
                    shi[j] = h;
                    slo[j] = (__bf16)(s[j] - (float)h);
                }
                *(bf16x8*)(sAhi + off) = shi;
                *(bf16x8*)(sAlo + off) = slo;
            } else {
                *(bf16x8*)(sAhi + off) = *(const bf16x8*)&Ahi[(size_t)g * 128 + k0 + k];
                *(bf16x8*)(sAlo + off) = *(const bf16x8*)&Alo[(size_t)g * 128 + k0 + k];
            }
        }
        // ---- stage W tile (128 x 64) ----
#pragma unroll
        for (int it = 0; it < 4; ++it) {
            int lin = it * 2048 + tid * 8;
            int n = lin >> 6, kk = lin & 63;
            int off = n * 64 + (((kk >> 3) ^ (n & 7)) << 3);
            *(bf16x8*)(sWhi + off) = *(const bf16x8*)&Wthi[(size_t)n * K + k0 + kk];
            *(bf16x8*)(sWlo + off) = *(const bf16x8*)&Wtlo[(size_t)n * K + k0 + kk];
        }
        __syncthreads();

#pragma unroll
        for (int s = 0; s < 2; ++s) {
            int sw = (((s * 4 + q) ^ axor) << 3);
            bf16x8 ahi = *(bf16x8*)(sAhi + arow * 64 + sw);
            bf16x8 alo = *(bf16x8*)(sAlo + arow * 64 + sw);
#pragma unroll
            for (int t = 0; t < 8; ++t) {
                int n = t * 16 + m16;
                bf16x8 bhi = *(bf16x8*)(sWhi + n * 64 + sw);
                bf16x8 blo = *(bf16x8*)(sWlo + n * 64 + sw);
                acc[t] = __builtin_amdgcn_mfma_f32_16x16x32_bf16(ahi, bhi, acc[t], 0, 0, 0);
                acc[t] = __builtin_amdgcn_mfma_f32_16x16x32_bf16(alo, bhi, acc[t], 0, 0, 0);
                acc[t] = __builtin_amdgcn_mfma_f32_16x16x32_bf16(ahi, blo, acc[t], 0, 0, 0);
            }
        }
        __syncthreads();
    }

    // ---- epilogue: bias + relu -> fp32 LDS -> coalesced bf16 hi/lo ----
    float* eps = (float*)(smem + 16384);  // 64*128*4 = 32KB
#pragma unroll
    for (int t = 0; t < 8; ++t) {
        int col = t * 16 + m16;
        float bb = bias[col];
#pragma unroll
        for (int i = 0; i < 4; ++i) {
            int row = wave * 16 + q * 4 + i;
            eps[row * 128 + col] = fmaxf(acc[t][i] + bb, 0.f);
        }
    }
    __syncthreads();
#pragma unroll
    for (int it = 0; it < 8; ++it) {
        int lin = it * 1024 + tid * 4;
        int row = lin >> 7, col = lin & 127;
        int g = row0 + row;
        if (g < M) {
            float4 v = *(float4*)(eps + lin);
            bf16x4 hi, lo;
            float vv[4] = {v.x, v.y, v.z, v.w};
#pragma unroll
            for (int j = 0; j < 4; ++j) {
                __bf16 h = (__bf16)vv[j];
                hi[j] = h;
                lo[j] = (__bf16)(vv[j] - (float)h);
            }
            *(bf16x4*)&Ohi[(size_t)g * 128 + col] = hi;
            *(bf16x4*)&Olo[(size_t)g * 128 + col] = lo;
        }
    }
}

// ===========================================================================
// Final GIN-layer GEMM fused with the output layer:
//   h' = relu(A @ W + b)   (kept in fp32 LDS, never written to global)
//   logits = h' @ W_out + b_out ; out = log_softmax(logits)
// Saves one dispatch + 51 MB h-write + 38 MB out-read, and improves accuracy
// (no bf16 round-trip of the last h).
// LDS 56KB -> 2 blocks/CU (last layer only).
// ===========================================================================
__global__ __launch_bounds__(256) void gemm_out(
    const __bf16* __restrict__ Ahi, const __bf16* __restrict__ Alo,
    const __bf16* __restrict__ Wthi, const __bf16* __restrict__ Wtlo,
    const float* __restrict__ bias,
    const float* __restrict__ Wout, const float* __restrict__ bout,
    float* __restrict__ out, int M) {
    __shared__ __align__(16) char smem[57344];
    __bf16* sAhi = (__bf16*)smem;                // 64x64 = 8KB
    __bf16* sAlo = (__bf16*)(smem + 8192);       // 8KB
    __bf16* sWhi = (__bf16*)(smem + 16384);      // 128x64 = 16KB
    __bf16* sWlo = (__bf16*)(smem + 32768);      // 16KB (K-loop ends at 48KB)

    int tid = threadIdx.x;
    int row0 = blockIdx.x * 64;
    int wave = tid >> 6;
    int l = tid & 63;
    int m16 = l & 15;
    int q = l >> 4;
    int axor = m16 & 7;
    int arow = wave * 16 + m16;

    floatx4 acc[8];
#pragma unroll
    for (int t = 0; t < 8; ++t) acc[t] = (floatx4){0.f, 0.f, 0.f, 0.f};

    for (int k0 = 0; k0 < 128; k0 += 64) {
        // ---- stage A tile (64 x 64), bf16 hi/lo pure copy ----
#pragma unroll
        for (int it = 0; it < 2; ++it) {
            int lin = it * 2048 + tid * 8;
            int row = lin >> 6, k = lin & 63;
            int g = min(row0 + row, M - 1);
            int off = row * 64 + (((k >> 3) ^ (row & 7)) << 3);
            *(bf16x8*)(sAhi + off) = *(const bf16x8*)&Ahi[(size_t)g * 128 + k0 + k];
            *(bf16x8*)(sAlo + off) = *(const bf16x8*)&Alo[(size_t)g * 128 + k0 + k];
        }
        // ---- stage W tile (128 x 64) ----
#pragma unroll
        for (int it = 0; it < 4; ++it) {
            int lin = it * 2048 + tid * 8;
            int n = lin >> 6, kk = lin & 63;
            int off = n * 64 + (((kk >> 3) ^ (n & 7)) << 3);
            *(bf16x8*)(sWhi + off) = *(const bf16x8*)&Wthi[(size_t)n * 128 + k0 + kk];
            *(bf16x8*)(sWlo + off) = *(const bf16x8*)&Wtlo[(size_t)n * 128 + k0 + kk];
        }
        __syncthreads();

#pragma unroll
        for (int s = 0; s < 2; ++s) {
            int sw = (((s * 4 + q) ^ axor) << 3);
            bf16x8 ahi = *(bf16x8*)(sAhi + arow * 64 + sw);
            bf16x8 alo = *(bf16x8*)(sAlo + arow * 64 + sw);
#pragma unroll
            for (int t = 0; t < 8; ++t) {
                int n = t * 16 + m16;
                bf16x8 bhi = *(bf16x8*)(sWhi + n * 64 + sw);
                bf16x8 blo = *(bf16x8*)(sWlo + n * 64 + sw);
                acc[t] = __builtin_amdgcn_mfma_f32_16x16x32_bf16(ahi, bhi, acc[t], 0, 0, 0);
                acc[t] = __builtin_amdgcn_mfma_f32_16x16x32_bf16(alo, bhi, acc[t], 0, 0, 0);
                acc[t] = __builtin_amdgcn_mfma_f32_16x16x32_bf16(ahi, blo, acc[t], 0, 0, 0);
            }
        }
        __syncthreads();
    }

    // ---- epilogue A: bias + relu -> fp32 LDS (stride 132 to break banks) ----
    float* eps = (float*)smem;                    // 64*132*4 = 33792 B
    float* sWo = (float*)(smem + 34816);          // 128*40*4 = 20480 B
    float* sb  = (float*)(smem + 55296);          // 40*4
#pragma unroll
    for (int t = 0; t < 8; ++t) {
        int col = t * 16 + m16;
        float bb = bias[col];
#pragma unroll
        for (int i = 0; i < 4; ++i) {
            int row = wave * 16 + q * 4 + i;
            eps[row * 132 + col] = fmaxf(acc[t][i] + bb, 0.f);
        }
    }
    // stage W_out / b_out (region disjoint from eps)
    for (int i = tid; i < 128 * NCLASS; i += 256) sWo[i] = Wout[i];
    if (tid < NCLASS) sb[tid] = bout[tid];
    __syncthreads();

    // ---- epilogue B: logits + log_softmax. 4 lanes/row, 10 classes/lane ----
    int r = tid >> 2;        // 0..63
    int cg = tid & 3;        // class group
    float z[10];
#pragma unroll
    for (int j = 0; j < 10; ++j) z[j] = sb[cg * 10 + j];
    for (int k = 0; k < 128; ++k) {
        float a = eps[r * 132 + k];
#pragma unroll
        for (int j = 0; j < 10; ++j) z[j] += a * sWo[k * NCLASS + cg * 10 + j];
    }
    float m = z[0];
#pragma unroll
    for (int j = 1; j < 10; ++j) m = fmaxf(m, z[j]);
    m = fmaxf(m, __shfl_xor(m, 1));
    m = fmaxf(m, __shfl_xor(m, 2));
    float s = 0.f;
#pragma unroll
    for (int j = 0; j < 10; ++j) s += expf(z[j] - m);
    s += __shfl_xor(s, 1);
    s += __shfl_xor(s, 2);
    float lse = m + logf(s);
    int row = row0 + r;
    if (row < M) {
#pragma unroll
        for (int j = 0; j < 10; ++j) out[(size_t)row * NCLASS + cg * 10 + j] = z[j] - lse;
    }
}

// ===========================================================================
extern "C" void kernel_launch(void* const* d_in, const int* in_sizes, int n_in,
                              void* d_out, int out_size, void* d_ws, size_t ws_size,
                              hipStream_t stream) {
    const float* x      = (const float*)d_in[0];
    const int*   esrc   = (const int*)d_in[1];
    const int*   edst   = (const int*)d_in[2];
    const float* W_in   = (const float*)d_in[3];
    const float* b_in   = (const float*)d_in[4];
    const float* W_mlps = (const float*)d_in[5];
    const float* b_mlps = (const float*)d_in[6];
    const float* W_out  = (const float*)d_in[7];
    const float* b_out  = (const float*)d_in[8];
    float* out = (float*)d_out;

    int N = in_sizes[0] / NFEAT;  // 50000
    int E = in_sizes[1];          // 800000
    int nbuck = (N + 255) >> 8;   // 196

    // workspace carve (~80.6 MB)
    char* ws = (char*)d_ws;
    size_t hb = (((size_t)N * NHID * sizeof(__bf16)) + 255) & ~(size_t)255;  // 12.8MB
    __bf16* h_hi_a = (__bf16*)ws;
    __bf16* h_lo_a = (__bf16*)(ws + hb);
    __bf16* h_hi_b = (__bf16*)(ws + 2 * hb);
    __bf16* h_lo_b = (__bf16*)(ws + 3 * hb);
    __bf16* sum_hi = (__bf16*)(ws + 4 * hb);
    __bf16* sum_lo = (__bf16*)(ws + 5 * hb);
    // bdata aliases sum_hi's slot: used only during CSR build (before any aggregate)
    unsigned int* bdata = (unsigned int*)(ws + 4 * hb);
    char* ip = ws + 6 * hb;
    int* row_ptr = (int*)ip;  ip += (((size_t)(N + 1) * 4) + 255) & ~(size_t)255;
    int* srcs    = (int*)ip;  ip += (((size_t)E * 4) + 255) & ~(size_t)255;
    int* bucket_counts = (int*)ip;  ip += 1024;
    int* bucket_start  = (int*)ip;  ip += 1024;
    int* bucket_cursor = (int*)ip;  ip += 1024;
    __bf16* Wt_in_hi   = (__bf16*)ip;  ip += 128 * NFEAT * 2;
    __bf16* Wt_in_lo   = (__bf16*)ip;  ip += 128 * NFEAT * 2;
    __bf16* Wt_mlps_hi = (__bf16*)ip;  ip += 3 * 128 * NHID * 2;
    __bf16* Wt_mlps_lo = (__bf16*)ip;  ip += 3 * 128 * NHID * 2;

    int eb4 = (E + 4095) / 4096;

    // ---- CSR build (bucketed counting sort) ----
    hipMemsetAsync(bucket_counts, 0, 1024, stream);
    bucket_hist<<<eb4, 256, 0, stream>>>(edst, bucket_counts, E, nbuck);
    bucket_scan<<<1, 256, 0, stream>>>(bucket_counts, bucket_start, bucket_cursor,
                                       row_ptr, nbuck, E, N);
    bucket_scatter<<<eb4, 256, 0, stream>>>(esrc, edst, bucket_cursor, bdata, E, nbuck);
    bucket_finalize<<<nbuck, 256, 0, stream>>>(bdata, bucket_start, row_ptr, srcs, N);

    // ---- weight prep (one dispatch) ----
    transpose_split_all<<<(128 * NFEAT + 3 * 128 * NHID + 255) / 256, 256, 0, stream>>>(
        W_in, W_mlps, Wt_in_hi, Wt_in_lo, Wt_mlps_hi, Wt_mlps_lo);

    int gb = (N + 63) / 64;
    // ---- input layer ----
    gemm_mfma<0><<<gb, 256, 0, stream>>>(x, (const __bf16*)nullptr, (const __bf16*)nullptr,
                                         Wt_in_hi, Wt_in_lo, b_in, h_hi_a, h_lo_a, N, NFEAT);

    // ---- GIN layers 0,1 (aggregate + gemm) ----
    __bf16* cur_hi = h_hi_a; __bf16* cur_lo = h_lo_a;
    __bf16* nxt_hi = h_hi_b; __bf16* nxt_lo = h_lo_b;
    for (int i = 0; i < 2; ++i) {
        aggregate_fused<<<(N + 3) / 4, 256, 0, stream>>>(cur_hi, cur_lo, row_ptr, srcs,
                                                         sum_hi, sum_lo, N);
        gemm_mfma<1><<<gb, 256, 0, stream>>>(
            (const float*)nullptr, sum_hi, sum_lo,
            Wt_mlps_hi + (size_t)i * 128 * NHID, Wt_mlps_lo + (size_t)i * 128 * NHID,
            b_mlps + (size_t)i * NHID, nxt_hi, nxt_lo, N, NHID);
        __bf16* t;
        t = cur_hi; cur_hi = nxt_hi; nxt_hi = t;
        t = cur_lo; cur_lo = nxt_lo; nxt_lo = t;
    }

    // ---- GIN layer 2 fused with output layer + log_softmax ----
    aggregate_fused<<<(N + 3) / 4, 256, 0, stream>>>(cur_hi, cur_lo, row_ptr, srcs,
                                                     sum_hi, sum_lo, N);
    gemm_out<<<gb, 256, 0, stream>>>(sum_hi, sum_lo,
                                     Wt_mlps_hi + (size_t)2 * 128 * NHID,
                                     Wt_mlps_lo + (size_t)2 * 128 * NHID,
                                     b_mlps + (size_t)2 * NHID,
                                     W_out, b_out, out, N);
}